// Round 14
// baseline (485.122 us; speedup 1.0000x reference)
//
#include <hip/hip_runtime.h>
#include <hip/hip_fp16.h>

#define NPIX (4*128*128)          // 65536
#define OUT_ELEMS (NPIX*64)       // 4194304

typedef _Float16 half8 __attribute__((ext_vector_type(8)));
typedef float f32x16 __attribute__((ext_vector_type(16)));

__device__ __forceinline__ int div25(int v) { return (v * 5243) >> 17; }   // exact 0..2600
__device__ __forceinline__ int div5(int v)  { return (v * 205) >> 10; }    // exact 0..1000

// ---------------------------------------------------------------------------
// K1: 1x1 convs q/k/v + out-init (out = x, fold target). 8 px/wave.
// ---------------------------------------------------------------------------
__global__ __launch_bounds__(256) void k1_qkv(
    const float* __restrict__ x,
    const float* __restrict__ Wq, const float* __restrict__ bq,
    const float* __restrict__ Wk, const float* __restrict__ bk,
    const float* __restrict__ Wv, const float* __restrict__ bv,
    float* __restrict__ qws, float* __restrict__ kws, float* __restrict__ vws,
    float* __restrict__ out_init)
{
    __shared__ float sWv[64 * 65];
    __shared__ float sWqk[16 * 65];

    int t = threadIdx.x;
    for (int e = t; e < 64 * 64; e += 256) sWv[(e >> 6) * 65 + (e & 63)] = Wv[e];
    for (int e = t; e < 8 * 64; e += 256) {
        int o = e >> 6, c = e & 63;
        sWqk[o * 65 + c]       = Wq[e];
        sWqk[(o + 8) * 65 + c] = Wk[e];
    }
    __syncthreads();

    int wid = t >> 6, lane = t & 63;
    bool isq = lane < 8;
    bool isk = (lane >= 8) && (lane < 16);
    const float* wr  = sWv + lane * 65;
    const float* wr2 = sWqk + (lane & 7) * 65 + (isk ? 8 * 65 : 0);
    float bvl = bv[lane];
    float bql = isq ? bq[lane] : (isk ? bk[lane - 8] : 0.f);

    #pragma unroll 1
    for (int i = 0; i < 8; ++i) {
        int pix = blockIdx.x * 32 + wid * 8 + i;
        float xv = x[(size_t)pix * 64 + lane];
        float accv = bvl, accq = bql;
        #pragma unroll
        for (int cc = 0; cc < 64; ++cc) {
            float xc = __shfl(xv, cc);
            accv = fmaf(xc, wr[cc], accv);
            accq = fmaf(xc, wr2[cc], accq);
        }
        vws[(size_t)pix * 64 + lane] = accv;
        out_init[(size_t)pix * 64 + lane] = xv;       // fold target = x
        if (isq)      qws[(size_t)pix * 8 + lane] = accq;
        else if (isk) kws[(size_t)pix * 8 + (lane - 8)] = accq;
    }
}

// ---------------------------------------------------------------------------
// K2: per-pixel attention, barrier-free, 5-blocks/CU [R9 core], with the
// fold done by 25 lane-coalesced global atomicAdds (no lws, no k3).
// Per-wave LDS W[1984 floats]:
//   Qs[0:200]  Kt[200:424] ([8][28])  E[424:1152] ([26][28], pads zeroed)
//   R[1152:1184]  Vth = (half*)(W+1184): 1600 halves (aliased later as LBh)
// MFMA garbage-safety: A rows m>=25 garbage -> D rows >=25 garbage -> dropped;
// k-dim pads zeroed; B rows k>=25 reg-masked to 0.
// ---------------------------------------------------------------------------
__global__ __launch_bounds__(256) void k2_attn_fold(
    const float* __restrict__ qws, const float* __restrict__ kws,
    const float* __restrict__ vws, const float* __restrict__ gamma,
    float* __restrict__ attn, float* __restrict__ out)
{
    __shared__ float smem[4 * 1984];

    int tid = threadIdx.x, wid = tid >> 6, lane = tid & 63;
    float* W   = smem + wid * 1984;
    float* Qs  = W;                 // [200]
    float* Kt  = W + 200;           // [8][28]
    float* E   = W + 424;           // [26][28]
    float* R   = W + 1152;          // [32]
    __half* Vth = (__half*)(W + 1184);  // [1600] halves
    __half* LBh = Vth;                   // alias (Vth dead after MFMA)

    int pix = blockIdx.x * 4 + wid;
    int b = pix >> 14, y = (pix >> 7) & 127, x = pix & 127;
    size_t ibase = (size_t)b << 14;

    // ---- zero the k-dim pad: cols 25..27 of rows 0..24, and all of row 25
    if (lane < 25) {
        float* er = E + lane * 28;
        er[25] = 0.f; er[26] = 0.f; er[27] = 0.f;
    }
    if (lane < 28) E[700 + lane] = 0.f;

    // ---- stage V as fp16 flat1600: Vth[lane*25 + p] = v(lane, patch p)
    const float* vb = vws + ibase * 64;
    int vbase = lane * 25;
    #pragma unroll
    for (int p = 0; p < 25; ++p) {
        int i5 = div5(p);
        int yy = y + i5 - 2, xx = x + (p - i5 * 5) - 2;
        float val = 0.f;
        if ((unsigned)yy < 128u && (unsigned)xx < 128u)
            val = vb[(size_t)(((yy << 7) + xx) * 64 + lane)];
        Vth[vbase + p] = __float2half(val);
    }

    // ---- stage Q flat, K transposed (both fp32 — exact logits path)
    const float* qb = qws + ibase * 8;
    const float* kb = kws + ibase * 8;
    #pragma unroll
    for (int i = 0; i < 4; ++i) {
        int e = lane + (i << 6);
        if (e < 200) {
            int cq = div25(e), p = e - cq * 25;
            int i5 = div5(p);
            int yy = y + i5 - 2, xx = x + (p - i5 * 5) - 2;
            float qv = 0.f, kv = 0.f;
            if ((unsigned)yy < 128u && (unsigned)xx < 128u) {
                int off = ((yy << 7) + xx) * 8 + cq;
                qv = qb[off];
                kv = kb[off];
            }
            Qs[e] = qv;
            Kt[(e & 7) * 28 + (e >> 3)] = kv;
        }
    }

    // ---- logits: lane = (m, row-half); K-column in registers.
    {
        bool act = lane < 50;
        int m_l = (lane < 25) ? lane : lane - 25;
        int n0  = (lane < 25) ? 0 : 13;
        float kreg[8];
        #pragma unroll
        for (int cc = 0; cc < 8; ++cc)
            kreg[cc] = Kt[cc * 28 + m_l];
        #pragma unroll
        for (int t = 0; t < 13; ++t) {
            int n = n0 + t;
            bool ok = act && (n < 25);
            int nn = ok ? n : 0;
            const float4* qr = (const float4*)(Qs + (nn << 3));
            float4 q0 = qr[0], q1 = qr[1];
            float s = q0.x * kreg[0] + q0.y * kreg[1] + q0.z * kreg[2] + q0.w * kreg[3]
                    + q1.x * kreg[4] + q1.y * kreg[5] + q1.z * kreg[6] + q1.w * kreg[7];
            if (ok) E[n * 28 + m_l] = s;
        }
    }

    // ---- softmax: 2 lanes per row (lanes 0..49)
    if (lane < 50) {
        int n = lane >> 1, hf = lane & 1;
        float* row = E + n * 28;
        int m0 = hf * 12;
        float mx = -3.4e38f;
        #pragma unroll
        for (int t = 0; t < 13; ++t) mx = fmaxf(mx, row[m0 + t]);
        mx = fmaxf(mx, __shfl_xor(mx, 1));
        float sum = 0.f;
        #pragma unroll
        for (int t = 0; t < 13; ++t) {
            int m = m0 + t;
            float ev = __expf(row[m] - mx);
            row[m] = ev;
            sum += (hf && t == 0) ? 0.f : ev;
        }
        sum += __shfl_xor(sum, 1);
        R[n] = 1.f / sum;
    }

    // ---- attn output (fp32, exact path)
    float* ab = attn + (size_t)pix * 625;
    #pragma unroll
    for (int i = 0; i < 10; ++i) {
        int e = lane + (i << 6);
        if (e < 625) {
            int n = div25(e), m = e - n * 25;
            ab[e] = E[n * 28 + m] * R[n];
        }
    }

    // ---- PV via MFMA. A = exp rows (f16); B[k][cc] = Vth[k*64+cc] (linear)
    int h  = lane >> 5;
    int lo = lane & 31;

    half8 afr[2];
    #pragma unroll
    for (int s = 0; s < 2; ++s) {
        const float4* ep = (const float4*)(E + lo * 28 + 16 * s + 8 * h);
        float4 p0 = ep[0], p1 = ep[1];
        afr[s][0] = (_Float16)p0.x; afr[s][1] = (_Float16)p0.y;
        afr[s][2] = (_Float16)p0.z; afr[s][3] = (_Float16)p0.w;
        afr[s][4] = (_Float16)p1.x; afr[s][5] = (_Float16)p1.y;
        afr[s][6] = (_Float16)p1.z; afr[s][7] = (_Float16)p1.w;
    }

    f32x16 acc0 = {0,0,0,0,0,0,0,0,0,0,0,0,0,0,0,0};
    f32x16 acc1 = {0,0,0,0,0,0,0,0,0,0,0,0,0,0,0,0};
    #pragma unroll
    for (int s = 0; s < 2; ++s) {
        half8 b0, b1;
        #pragma unroll
        for (int j = 0; j < 8; ++j) {
            int k = 16 * s + 8 * h + j;            // logical k row
            bool ok = (k < 25);
            int off = ok ? (((16 * s + j) << 6) + (h << 9)) : 0;   // in-bounds clamp
            _Float16 v0 = Vth[off + lo];
            _Float16 v1 = Vth[off + 32 + lo];
            b0[j] = ok ? v0 : (_Float16)0.f;       // B rows k>=25 MUST be 0
            b1[j] = ok ? v1 : (_Float16)0.f;
        }
        acc0 = __builtin_amdgcn_mfma_f32_32x32x16_f16(afr[s], b0, acc0, 0, 0, 0);
        acc1 = __builtin_amdgcn_mfma_f32_32x32x16_f16(afr[s], b1, acc1, 0, 0, 0);
    }

    // ---- fold-remap in fp16 (gamma folded in): LBh[n*64+cc] = acc*R[n]*g
    float g0 = gamma[0];
    #pragma unroll
    for (int r16 = 0; r16 < 16; ++r16) {
        int row = (r16 & 3) + 8 * (r16 >> 2) + 4 * h;
        if (row < 25) {
            float rg = R[row] * g0;
            LBh[(row << 6) + lo]      = __float2half(acc0[r16] * rg);
            LBh[(row << 6) + 32 + lo] = __float2half(acc1[r16] * rg);
        }
    }

    // ---- fold scatter: 25 lane-coalesced atomic adds into out (= x + ...)
    float* ob = out + ibase * 64;
    #pragma unroll
    for (int p = 0; p < 25; ++p) {
        int i5 = div5(p);
        int ty = y + i5 - 2, tx = x + (p - i5 * 5) - 2;
        if ((unsigned)ty < 128u && (unsigned)tx < 128u)
            atomicAdd(ob + (size_t)(((ty << 7) + tx) * 64 + lane),
                      __half2float(LBh[lane * 25 + p]));
    }
}

// ---------------------------------------------------------------------------
extern "C" void kernel_launch(void* const* d_in, const int* in_sizes, int n_in,
                              void* d_out, int out_size, void* d_ws, size_t ws_size,
                              hipStream_t stream)
{
    const float* x  = (const float*)d_in[0];
    const float* Wq = (const float*)d_in[1];
    const float* bq = (const float*)d_in[2];
    const float* Wk = (const float*)d_in[3];
    const float* bk = (const float*)d_in[4];
    const float* Wv = (const float*)d_in[5];
    const float* bv = (const float*)d_in[6];
    const float* gm = (const float*)d_in[7];

    float* out  = (float*)d_out;               // [4,128,128,64]
    float* attn = out + OUT_ELEMS;             // [4,128,128,25,25]

    float* qws = (float*)d_ws;                 // [NPIX][8]
    float* kws = qws + (size_t)NPIX * 8;       // [NPIX][8]
    float* vws = kws + (size_t)NPIX * 8;       // [NPIX][64]  (20.97 MB total)

    hipLaunchKernelGGL(k1_qkv, dim3(NPIX / 32), dim3(256), 0, stream,
                       x, Wq, bq, Wk, bk, Wv, bv, qws, kws, vws, out);
    hipLaunchKernelGGL(k2_attn_fold, dim3(NPIX / 4), dim3(256), 0, stream,
                       qws, kws, vws, gm, attn, out);
}

// Round 16
// 259.684 us; speedup vs baseline: 1.8681x; 1.8681x over previous
//
#include <hip/hip_runtime.h>
#include <hip/hip_fp16.h>

#define NPIX (4*128*128)          // 65536
#define OUT_ELEMS (NPIX*64)       // 4194304

typedef _Float16 half8 __attribute__((ext_vector_type(8)));
typedef float f32x16 __attribute__((ext_vector_type(16)));

__device__ __forceinline__ int div25(int v) { return (v * 5243) >> 17; }   // exact 0..2600
__device__ __forceinline__ int div5(int v)  { return (v * 205) >> 10; }    // exact 0..1000

// ---------------------------------------------------------------------------
// K1: 1x1 convs q/k/v. 2048 blocks; each wave handles 8 pixels.  [R13 exact]
// ---------------------------------------------------------------------------
__global__ __launch_bounds__(256) void k1_qkv(
    const float* __restrict__ x,
    const float* __restrict__ Wq, const float* __restrict__ bq,
    const float* __restrict__ Wk, const float* __restrict__ bk,
    const float* __restrict__ Wv, const float* __restrict__ bv,
    float* __restrict__ qws, float* __restrict__ kws, float* __restrict__ vws,
    float* __restrict__ out_init)
{
    __shared__ float sWv[64 * 65];
    __shared__ float sWqk[16 * 65];

    int t = threadIdx.x;
    for (int e = t; e < 64 * 64; e += 256) sWv[(e >> 6) * 65 + (e & 63)] = Wv[e];
    for (int e = t; e < 8 * 64; e += 256) {
        int o = e >> 6, c = e & 63;
        sWqk[o * 65 + c]       = Wq[e];
        sWqk[(o + 8) * 65 + c] = Wk[e];
    }
    __syncthreads();

    int wid = t >> 6, lane = t & 63;
    bool isq = lane < 8;
    bool isk = (lane >= 8) && (lane < 16);
    const float* wr  = sWv + lane * 65;
    const float* wr2 = sWqk + (lane & 7) * 65 + (isk ? 8 * 65 : 0);
    float bvl = bv[lane];
    float bql = isq ? bq[lane] : (isk ? bk[lane - 8] : 0.f);

    #pragma unroll 1
    for (int i = 0; i < 8; ++i) {
        int pix = blockIdx.x * 32 + wid * 8 + i;
        float xv = x[(size_t)pix * 64 + lane];
        float accv = bvl, accq = bql;
        #pragma unroll
        for (int cc = 0; cc < 64; ++cc) {
            float xc = __shfl(xv, cc);
            accv = fmaf(xc, wr[cc], accv);
            accq = fmaf(xc, wr2[cc], accq);
        }
        vws[(size_t)pix * 64 + lane] = accv;
        if (out_init) out_init[(size_t)pix * 64 + lane] = xv;
        if (isq)      qws[(size_t)pix * 8 + lane] = accq;
        else if (isk) kws[(size_t)pix * 8 + (lane - 8)] = accq;
    }
}

// ---------------------------------------------------------------------------
// K2: per-pixel attention, barrier-free, 5-blocks/CU. [R13 core, verbatim
// except the B-frag s=0 sub-loop drops its provably-dead mask/clamp:
// s=0 -> k = 8h+j <= 15 < 25 for h in {0,1}.]
// Per-wave LDS W[1984 floats]:
//   Qs[0:200]  Kt[200:424] ([8][28])  E[424:1152] ([26][28], pads zeroed)
//   R[1152:1184]  Vth = (half*)(W+1184): 1600 halves (aliased later as LBh)
// MFMA garbage-safety: A rows m>=25 garbage -> D rows >=25 garbage -> dropped;
// k-dim pads zeroed; B rows k>=25 reg-masked to 0.
// The LBh remap bounce is MANDATORY: it applies the raw-reshape permutation
// flat[n*64+cc] -> plane layout [p=g%25][c=g/25] (not a row/col relabel).
// ---------------------------------------------------------------------------
__global__ __launch_bounds__(256) void k2_attn_ws(
    const float* __restrict__ qws, const float* __restrict__ kws,
    const float* __restrict__ vws,
    float* __restrict__ attn, __half* __restrict__ lws)
{
    __shared__ float smem[4 * 1984];

    int tid = threadIdx.x, wid = tid >> 6, lane = tid & 63;
    float* W   = smem + wid * 1984;
    float* Qs  = W;                 // [200]
    float* Kt  = W + 200;           // [8][28]
    float* E   = W + 424;           // [26][28]
    float* R   = W + 1152;          // [32]
    __half* Vth = (__half*)(W + 1184);  // [1600] halves
    __half* LBh = Vth;                   // alias (Vth dead after MFMA)

    int pix = blockIdx.x * 4 + wid;
    int b = pix >> 14, y = (pix >> 7) & 127, x = pix & 127;
    size_t ibase = (size_t)b << 14;

    // ---- zero the k-dim pad: cols 25..27 of rows 0..24, and all of row 25
    if (lane < 25) {
        float* er = E + lane * 28;
        er[25] = 0.f; er[26] = 0.f; er[27] = 0.f;
    }
    if (lane < 28) E[700 + lane] = 0.f;

    // ---- stage V as fp16 flat1600: Vth[lane*25 + p] = v(lane, patch p)
    const float* vb = vws + ibase * 64;
    int vbase = lane * 25;
    #pragma unroll
    for (int p = 0; p < 25; ++p) {
        int i5 = div5(p);
        int yy = y + i5 - 2, xx = x + (p - i5 * 5) - 2;
        float val = 0.f;
        if ((unsigned)yy < 128u && (unsigned)xx < 128u)
            val = vb[(size_t)(((yy << 7) + xx) * 64 + lane)];
        Vth[vbase + p] = __float2half(val);
    }

    // ---- stage Q flat, K transposed (both fp32 — exact logits path)
    const float* qb = qws + ibase * 8;
    const float* kb = kws + ibase * 8;
    #pragma unroll
    for (int i = 0; i < 4; ++i) {
        int e = lane + (i << 6);
        if (e < 200) {
            int cq = div25(e), p = e - cq * 25;
            int i5 = div5(p);
            int yy = y + i5 - 2, xx = x + (p - i5 * 5) - 2;
            float qv = 0.f, kv = 0.f;
            if ((unsigned)yy < 128u && (unsigned)xx < 128u) {
                int off = ((yy << 7) + xx) * 8 + cq;
                qv = qb[off];
                kv = kb[off];
            }
            Qs[e] = qv;
            Kt[(e & 7) * 28 + (e >> 3)] = kv;
        }
    }

    // ---- logits: lane = (m, row-half); K-column in registers.
    {
        bool act = lane < 50;
        int m_l = (lane < 25) ? lane : lane - 25;
        int n0  = (lane < 25) ? 0 : 13;
        float kreg[8];
        #pragma unroll
        for (int cc = 0; cc < 8; ++cc)
            kreg[cc] = Kt[cc * 28 + m_l];
        #pragma unroll
        for (int t = 0; t < 13; ++t) {
            int n = n0 + t;
            bool ok = act && (n < 25);
            int nn = ok ? n : 0;
            const float4* qr = (const float4*)(Qs + (nn << 3));
            float4 q0 = qr[0], q1 = qr[1];
            float s = q0.x * kreg[0] + q0.y * kreg[1] + q0.z * kreg[2] + q0.w * kreg[3]
                    + q1.x * kreg[4] + q1.y * kreg[5] + q1.z * kreg[6] + q1.w * kreg[7];
            if (ok) E[n * 28 + m_l] = s;
        }
    }

    // ---- softmax: 2 lanes per row (lanes 0..49)
    if (lane < 50) {
        int n = lane >> 1, hf = lane & 1;
        float* row = E + n * 28;
        int m0 = hf * 12;
        float mx = -3.4e38f;
        #pragma unroll
        for (int t = 0; t < 13; ++t) mx = fmaxf(mx, row[m0 + t]);
        mx = fmaxf(mx, __shfl_xor(mx, 1));
        float sum = 0.f;
        #pragma unroll
        for (int t = 0; t < 13; ++t) {
            int m = m0 + t;
            float ev = __expf(row[m] - mx);
            row[m] = ev;
            sum += (hf && t == 0) ? 0.f : ev;
        }
        sum += __shfl_xor(sum, 1);
        R[n] = 1.f / sum;
    }

    // ---- attn output (fp32, exact path)
    float* ab = attn + (size_t)pix * 625;
    #pragma unroll
    for (int i = 0; i < 10; ++i) {
        int e = lane + (i << 6);
        if (e < 625) {
            int n = div25(e), m = e - n * 25;
            ab[e] = E[n * 28 + m] * R[n];
        }
    }

    // ---- PV via MFMA. A = exp rows (f16); B[k][cc] = Vth[k*64+cc] (linear)
    int h  = lane >> 5;
    int lo = lane & 31;

    half8 afr[2];
    #pragma unroll
    for (int s = 0; s < 2; ++s) {
        const float4* ep = (const float4*)(E + lo * 28 + 16 * s + 8 * h);
        float4 p0 = ep[0], p1 = ep[1];
        afr[s][0] = (_Float16)p0.x; afr[s][1] = (_Float16)p0.y;
        afr[s][2] = (_Float16)p0.z; afr[s][3] = (_Float16)p0.w;
        afr[s][4] = (_Float16)p1.x; afr[s][5] = (_Float16)p1.y;
        afr[s][6] = (_Float16)p1.z; afr[s][7] = (_Float16)p1.w;
    }

    f32x16 acc0 = {0,0,0,0,0,0,0,0,0,0,0,0,0,0,0,0};
    f32x16 acc1 = {0,0,0,0,0,0,0,0,0,0,0,0,0,0,0,0};

    // s = 0: k = 8h + j <= 15 < 25 always -> no mask, no clamp.
    {
        half8 b0, b1;
        #pragma unroll
        for (int j = 0; j < 8; ++j) {
            int off = (j << 6) + (h << 9);         // k*64 = (8h+j)*64
            b0[j] = Vth[off + lo];
            b1[j] = Vth[off + 32 + lo];
        }
        acc0 = __builtin_amdgcn_mfma_f32_32x32x16_f16(afr[0], b0, acc0, 0, 0, 0);
        acc1 = __builtin_amdgcn_mfma_f32_32x32x16_f16(afr[0], b1, acc1, 0, 0, 0);
    }
    // s = 1: k = 16 + 8h + j; rows k >= 25 masked to 0 (A cols 28..31 spill).
    {
        half8 b0, b1;
        #pragma unroll
        for (int j = 0; j < 8; ++j) {
            int k = 16 + 8 * h + j;
            bool ok = (k < 25);
            int off = ok ? (((16 + j) << 6) + (h << 9)) : 0;   // in-bounds clamp
            _Float16 v0 = Vth[off + lo];
            _Float16 v1 = Vth[off + 32 + lo];
            b0[j] = ok ? v0 : (_Float16)0.f;
            b1[j] = ok ? v1 : (_Float16)0.f;
        }
        acc0 = __builtin_amdgcn_mfma_f32_32x32x16_f16(afr[1], b0, acc0, 0, 0, 0);
        acc1 = __builtin_amdgcn_mfma_f32_32x32x16_f16(afr[1], b1, acc1, 0, 0, 0);
    }

    // ---- fold-remap in fp16: LBh[n*64+cc] = (half)(acc*R[n]); aliases Vth.
    // MANDATORY permutation stage (flat[n*64+cc] -> [p][c] needs g%25,g/25).
    #pragma unroll
    for (int r16 = 0; r16 < 16; ++r16) {
        int row = (r16 & 3) + 8 * (r16 >> 2) + 4 * h;
        if (row < 25) {
            float rn = R[row];
            LBh[(row << 6) + lo]      = __float2half(acc0[r16] * rn);
            LBh[(row << 6) + 32 + lo] = __float2half(acc1[r16] * rn);
        }
    }

    // ---- store fp16 local, PLANE layout: lws[(p*NPIX + pix)*64 + c]
    #pragma unroll
    for (int p = 0; p < 25; ++p)
        lws[((size_t)p * NPIX + (size_t)pix) * 64 + lane] = LBh[lane * 25 + p];
}

// ---------------------------------------------------------------------------
// K3: gather fold, 8 pixels/wave. [R13 exact]
// ---------------------------------------------------------------------------
__global__ __launch_bounds__(256) void k3_fold(
    const float* __restrict__ x, const __half* __restrict__ lws,
    const float* __restrict__ gamma, float* __restrict__ out)
{
    int tid = threadIdx.x, wid = tid >> 6, lane = tid & 63;
    int pix8 = (blockIdx.x * 4 + wid) * 8;
    int b = pix8 >> 14, y = (pix8 >> 7) & 127, x0 = pix8 & 127;
    int sub = lane >> 3;            // pixel 0..7 within group (row-contiguous)
    int ch8 = (lane & 7) << 3;      // channel group (8 channels, 16 B)
    size_t ibase = (size_t)b << 14;

    float s[8] = {0.f,0.f,0.f,0.f,0.f,0.f,0.f,0.f};
    #pragma unroll
    for (int i = 0; i < 5; ++i) {
        int cy = y + 2 - i;
        if ((unsigned)cy >= 128u) continue;        // wave-uniform
        #pragma unroll
        for (int j = 0; j < 5; ++j) {
            int cx = x0 + sub + 2 - j;             // per-lane source pixel
            if ((unsigned)cx < 128u) {
                size_t src = ((size_t)(i * 5 + j) * NPIX + (ibase + (size_t)((cy << 7) + cx))) * 64 + ch8;
                float4 w = *(const float4*)(lws + src);   // 8 fp16
                const __half2* hp = (const __half2*)&w;
                #pragma unroll
                for (int q = 0; q < 4; ++q) {
                    float2 f = __half22float2(hp[q]);
                    s[2 * q]     += f.x;
                    s[2 * q + 1] += f.y;
                }
            }
        }
    }

    float g = gamma[0];
    size_t o = ((size_t)pix8 + sub) * 64 + ch8;
    float4 xv0 = *(const float4*)(x + o);
    float4 xv1 = *(const float4*)(x + o + 4);
    float4 r0, r1;
    r0.x = fmaf(g, s[0], xv0.x);
    r0.y = fmaf(g, s[1], xv0.y);
    r0.z = fmaf(g, s[2], xv0.z);
    r0.w = fmaf(g, s[3], xv0.w);
    r1.x = fmaf(g, s[4], xv1.x);
    r1.y = fmaf(g, s[5], xv1.y);
    r1.z = fmaf(g, s[6], xv1.z);
    r1.w = fmaf(g, s[7], xv1.w);
    *(float4*)(out + o)     = r0;
    *(float4*)(out + o + 4) = r1;
}

// ---------------------------------------------------------------------------
// Fallback path (small ws): R3's proven per-pixel attention + atomic fold.
// ---------------------------------------------------------------------------
__device__ __forceinline__ void attn_core_fb(
    int lane, int y, int x, size_t ibase,
    const float* __restrict__ qws, const float* __restrict__ kws,
    const float* __restrict__ vws, float* __restrict__ attn,
    float* V, float* Qs, float* Ks, float* E, float* R, float vr[25])
{
    const float* vb = vws + ibase * 64;
    #pragma unroll
    for (int p = 0; p < 25; ++p) {
        int i5 = div5(p);
        int yy = y + i5 - 2, xx = x + (p - i5 * 5) - 2;
        float val = 0.f;
        if ((unsigned)yy < 128u && (unsigned)xx < 128u)
            val = vb[(size_t)(((yy << 7) + xx) * 64 + lane)];
        V[p * 65 + lane] = val;
    }
    const float* qb = qws + ibase * 8;
    const float* kb = kws + ibase * 8;
    #pragma unroll
    for (int i = 0; i < 4; ++i) {
        int e = lane + (i << 6);
        if (e < 200) {
            int cq = div25(e), p = e - cq * 25;
            int i5 = div5(p);
            int yy = y + i5 - 2, xx = x + (p - i5 * 5) - 2;
            float qv = 0.f, kv = 0.f;
            if ((unsigned)yy < 128u && (unsigned)xx < 128u) {
                int off = ((yy << 7) + xx) * 8 + cq;
                qv = qb[off];
                kv = kb[off];
            }
            Qs[e] = qv;
            Ks[e] = kv;
        }
    }
    #pragma unroll
    for (int m = 0; m < 25; ++m) {
        int g = (m << 6) + lane;
        int cv = div25(g), p = g - cv * 25;
        vr[m] = V[p * 65 + cv];
    }
    #pragma unroll
    for (int i = 0; i < 10; ++i) {
        int e = lane + (i << 6);
        if (e < 625) {
            int n = div25(e), m = e - n * 25;
            const float4* qr = (const float4*)(Qs + (n << 3));
            const float4* kr = (const float4*)(Ks + (m << 3));
            float4 q0 = qr[0], q1 = qr[1], k0 = kr[0], k1 = kr[1];
            E[n * 28 + m] = q0.x * k0.x + q0.y * k0.y + q0.z * k0.z + q0.w * k0.w
                          + q1.x * k1.x + q1.y * k1.y + q1.z * k1.z + q1.w * k1.w;
        }
    }
    if (lane < 25) {
        float* row = E + lane * 28;
        float mx = -3.4e38f;
        #pragma unroll
        for (int m = 0; m < 25; ++m) mx = fmaxf(mx, row[m]);
        float s = 0.f;
        #pragma unroll
        for (int m = 0; m < 25; ++m) {
            float ev = __expf(row[m] - mx);
            row[m] = ev;
            s += ev;
        }
        R[lane] = 1.f / s;
    }
    float* ab = attn + (ibase + (size_t)((y << 7) + x)) * 625;
    #pragma unroll
    for (int i = 0; i < 10; ++i) {
        int e = lane + (i << 6);
        if (e < 625) {
            int n = div25(e), m = e - n * 25;
            ab[e] = E[n * 28 + m] * R[n];
        }
    }
}

__global__ __launch_bounds__(256) void k2_attn_atomic(
    const float* __restrict__ qws, const float* __restrict__ kws,
    const float* __restrict__ vws, const float* __restrict__ gamma,
    float* __restrict__ out, float* __restrict__ attn)
{
    __shared__ float sV[4][1632];
    __shared__ float sQ[4][200];
    __shared__ float sK[4][200];
    __shared__ float sE[4][704];
    __shared__ float sR[4][32];

    int tid = threadIdx.x, wid = tid >> 6, lane = tid & 63;
    int pix = blockIdx.x * 4 + wid;
    int b = pix >> 14, y = (pix >> 7) & 127, x = pix & 127;
    size_t ibase = (size_t)b << 14;

    float vr[25];
    attn_core_fb(lane, y, x, ibase, qws, kws, vws, attn,
                 sV[wid], sQ[wid], sK[wid], sE[wid], sR[wid], vr);

    float g0 = gamma[0];
    float acc[25];
    float* E = sE[wid];
    float* R = sR[wid];
    #pragma unroll
    for (int n = 0; n < 25; ++n) {
        const float4* er = (const float4*)(E + n * 28);
        float aa = E[n * 28 + 24] * vr[24];
        #pragma unroll
        for (int q4 = 0; q4 < 6; ++q4) {
            float4 ev = er[q4];
            aa = fmaf(ev.x, vr[q4 * 4 + 0], aa);
            aa = fmaf(ev.y, vr[q4 * 4 + 1], aa);
            aa = fmaf(ev.z, vr[q4 * 4 + 2], aa);
            aa = fmaf(ev.w, vr[q4 * 4 + 3], aa);
        }
        acc[n] = aa * (R[n] * g0);
    }

    float* LB = sV[wid];
    #pragma unroll
    for (int n = 0; n < 25; ++n) LB[(n << 6) + lane] = acc[n];

    float* ob = out + ibase * 64;
    #pragma unroll
    for (int p = 0; p < 25; ++p) {
        int i5 = div5(p);
        int ty = y + i5 - 2, tx = x + (p - i5 * 5) - 2;
        if ((unsigned)ty < 128u && (unsigned)tx < 128u)
            atomicAdd(ob + (size_t)(((ty << 7) + tx) * 64 + lane), LB[lane * 25 + p]);
    }
}

// ---------------------------------------------------------------------------
extern "C" void kernel_launch(void* const* d_in, const int* in_sizes, int n_in,
                              void* d_out, int out_size, void* d_ws, size_t ws_size,
                              hipStream_t stream)
{
    const float* x  = (const float*)d_in[0];
    const float* Wq = (const float*)d_in[1];
    const float* bq = (const float*)d_in[2];
    const float* Wk = (const float*)d_in[3];
    const float* bk = (const float*)d_in[4];
    const float* Wv = (const float*)d_in[5];
    const float* bv = (const float*)d_in[6];
    const float* gm = (const float*)d_in[7];

    float* out  = (float*)d_out;               // [4,128,128,64]
    float* attn = out + OUT_ELEMS;             // [4,128,128,25,25]

    float* qws = (float*)d_ws;                 // [NPIX][8]
    float* kws = qws + (size_t)NPIX * 8;       // [NPIX][8]
    float* vws = kws + (size_t)NPIX * 8;       // [NPIX][64]
    __half* lws = (__half*)(vws + (size_t)NPIX * 64);   // [25][NPIX][64] fp16 planes

    const size_t need = (size_t)NPIX * 80 * 4 + (size_t)NPIX * 1600 * 2; // 230.7 MB

    if (ws_size >= need) {
        hipLaunchKernelGGL(k1_qkv, dim3(NPIX / 32), dim3(256), 0, stream,
                           x, Wq, bq, Wk, bk, Wv, bv, qws, kws, vws, (float*)nullptr);
        hipLaunchKernelGGL(k2_attn_ws, dim3(NPIX / 4), dim3(256), 0, stream,
                           qws, kws, vws, attn, lws);
        hipLaunchKernelGGL(k3_fold, dim3(NPIX / 32), dim3(256), 0, stream,
                           x, lws, gm, out);
    } else {
        hipLaunchKernelGGL(k1_qkv, dim3(NPIX / 32), dim3(256), 0, stream,
                           x, Wq, bq, Wk, bk, Wv, bv, qws, kws, vws, out);
        hipLaunchKernelGGL(k2_attn_atomic, dim3(NPIX / 4), dim3(256), 0, stream,
                           qws, kws, vws, gm, out, attn);
    }
}